// Round 2
// baseline (442.173 us; speedup 1.0000x reference)
//
#include <hip/hip_runtime.h>

// S=4096, B=8, D=1024, BN=128; M = S*B = 32768 rows.
// Inputs/output fp32 (per reference); internal GEMMs in bf16 MFMA (threshold is 2%).
#define S_DIM 4096
#define B_DIM 8
#define D_DIM 1024
#define BN_DIM 128
#define M_DIM (S_DIM * B_DIM)

typedef short s8v __attribute__((ext_vector_type(8)));   // 8 x bf16 bits (4 VGPRs)
typedef float f4v __attribute__((ext_vector_type(4)));   // MFMA C/D frag

__device__ __forceinline__ unsigned short f2bf(float f) {
  union { unsigned int i; float f; } v; v.f = f;
  unsigned int r = v.i + 0x7FFFu + ((v.i >> 16) & 1u);  // round-nearest-even
  return (unsigned short)(r >> 16);
}
__device__ __forceinline__ float bf2f(unsigned short u) {
  union { unsigned int i; float f; } v; v.i = ((unsigned int)u) << 16; return v.f;
}

// ---------------------------------------------------------------------------
// Kernel 1: y = x + res^T (fp32); LayerNorm(y) -> norm (bf16, ws);
// y (fp32 shortcut) -> out buffer (reused as scratch). One wave per row.
// ---------------------------------------------------------------------------
__global__ __launch_bounds__(256) void add_ln_kernel(
    const float* __restrict__ x,     // [S,B,D] = [M,D]
    const float* __restrict__ res,   // [B,S,D]
    const float* __restrict__ gamma, // [D]
    const float* __restrict__ beta,  // [D]
    unsigned short* __restrict__ norm, // [M,D] bf16
    float* __restrict__ shortcut) {    // [M,D] fp32 (the out buffer)
  int wave = threadIdx.x >> 6, lane = threadIdx.x & 63;
  int row = blockIdx.x * 4 + wave;
  int s = row >> 3, b = row & 7;
  const float* xr = x + (size_t)row * D_DIM;
  const float* rr = res + ((size_t)b * S_DIM + s) * D_DIM;

  float4 v[4];
  float sum = 0.f, sumsq = 0.f;
#pragma unroll
  for (int c = 0; c < 4; ++c) {
    int e = c * 256 + lane * 4;
    float4 xv = *(const float4*)&xr[e];
    float4 rv = *(const float4*)&rr[e];
    v[c].x = xv.x + rv.x; v[c].y = xv.y + rv.y;
    v[c].z = xv.z + rv.z; v[c].w = xv.w + rv.w;
    sum += v[c].x + v[c].y + v[c].z + v[c].w;
    sumsq += v[c].x * v[c].x + v[c].y * v[c].y + v[c].z * v[c].z + v[c].w * v[c].w;
  }
#pragma unroll
  for (int ofs = 32; ofs >= 1; ofs >>= 1) {
    sum   += __shfl_xor(sum, ofs, 64);
    sumsq += __shfl_xor(sumsq, ofs, 64);
  }
  float mu   = sum * (1.f / D_DIM);
  float var  = sumsq * (1.f / D_DIM) - mu * mu;
  float rstd = rsqrtf(var + 1e-5f);

  float* sr = shortcut + (size_t)row * D_DIM;
  unsigned short* nr = norm + (size_t)row * D_DIM;
#pragma unroll
  for (int c = 0; c < 4; ++c) {
    int e = c * 256 + lane * 4;
    *(float4*)&sr[e] = v[c];
    float4 gv = *(const float4*)&gamma[e];
    float4 bv = *(const float4*)&beta[e];
    ushort4 o;
    o.x = f2bf((v[c].x - mu) * rstd * gv.x + bv.x);
    o.y = f2bf((v[c].y - mu) * rstd * gv.y + bv.y);
    o.z = f2bf((v[c].z - mu) * rstd * gv.z + bv.z);
    o.w = f2bf((v[c].w - mu) * rstd * gv.w + bv.w);
    *(ushort4*)&nr[e] = o;
  }
}

// ---------------------------------------------------------------------------
// Kernel 2: H = relu(norm @ W_down^T + b_down)  [M,128]; M-tiles of 64, N=128.
// ---------------------------------------------------------------------------
#define LDT 40  // padded LDS row stride (ushorts): 80B -> worst 2-way conflict (free)

__global__ __launch_bounds__(256) void gemm_down(
    const unsigned short* __restrict__ A,    // [M,1024] norm (bf16)
    const float* __restrict__ W,             // [128,1024] W_down (fp32, K-contig)
    const float* __restrict__ bias,          // [128] fp32
    unsigned short* __restrict__ H) {        // [M,128] bf16
  __shared__ unsigned short As[64 * LDT];
  __shared__ unsigned short Bs[128 * LDT];
  int t = threadIdx.x, wave = t >> 6, lane = t & 63;
  int tileM = blockIdx.x * 64;

  f4v acc[8];
#pragma unroll
  for (int i = 0; i < 8; ++i) acc[i] = (f4v){0.f, 0.f, 0.f, 0.f};

  int arow = t >> 2, akc = (t & 3) * 8;
  for (int kk = 0; kk < 1024; kk += 32) {
    *(s8v*)&As[arow * LDT + akc] =
        *(const s8v*)&A[(size_t)(tileM + arow) * 1024 + kk + akc];
#pragma unroll
    for (int i = 0; i < 2; ++i) {
      int idx = t + i * 256;
      int brow = idx >> 2, bkc = (idx & 3) * 8;
      const float* wp = &W[(size_t)brow * 1024 + kk + bkc];
      float4 w0 = *(const float4*)wp;
      float4 w1 = *(const float4*)(wp + 4);
      s8v bv;
      bv[0] = (short)f2bf(w0.x); bv[1] = (short)f2bf(w0.y);
      bv[2] = (short)f2bf(w0.z); bv[3] = (short)f2bf(w0.w);
      bv[4] = (short)f2bf(w1.x); bv[5] = (short)f2bf(w1.y);
      bv[6] = (short)f2bf(w1.z); bv[7] = (short)f2bf(w1.w);
      *(s8v*)&Bs[brow * LDT + bkc] = bv;
    }
    __syncthreads();
    int kq = (lane >> 4) * 8;
    s8v a = *(const s8v*)&As[(wave * 16 + (lane & 15)) * LDT + kq];
#pragma unroll
    for (int nt = 0; nt < 8; ++nt) {
      s8v b = *(const s8v*)&Bs[(nt * 16 + (lane & 15)) * LDT + kq];
      acc[nt] = __builtin_amdgcn_mfma_f32_16x16x32_bf16(a, b, acc[nt], 0, 0, 0);
    }
    __syncthreads();
  }
  // C[m = wave*16 + (lane>>4)*4 + r, n = nt*16 + (lane&15)]
#pragma unroll
  for (int nt = 0; nt < 8; ++nt) {
    int n = nt * 16 + (lane & 15);
    float bs = bias[n];
#pragma unroll
    for (int r = 0; r < 4; ++r) {
      int m = wave * 16 + (lane >> 4) * 4 + r;
      float val = acc[nt][r] + bs;
      val = val > 0.f ? val : 0.f;
      H[(size_t)(tileM + m) * BN_DIM + n] = f2bf(val);
    }
  }
}

// ---------------------------------------------------------------------------
// Kernel 3: out = H @ W_up^T + b_up + shortcut (out buffer holds shortcut).
// ---------------------------------------------------------------------------
__global__ __launch_bounds__(256) void gemm_up(
    const unsigned short* __restrict__ H,    // [M,128] bf16
    const float* __restrict__ W,             // [1024,128] W_up (fp32, K-contig)
    const float* __restrict__ bias,          // [1024] fp32
    float* __restrict__ out) {               // [M,1024] fp32, holds shortcut
  __shared__ unsigned short As[64 * LDT];
  __shared__ unsigned short Bs[128 * LDT];
  int t = threadIdx.x, wave = t >> 6, lane = t & 63;
  int tileM = blockIdx.x * 64;
  int tileN = blockIdx.y * 128;

  f4v acc[8];
#pragma unroll
  for (int i = 0; i < 8; ++i) acc[i] = (f4v){0.f, 0.f, 0.f, 0.f};

  int arow = t >> 2, akc = (t & 3) * 8;
#pragma unroll
  for (int kk = 0; kk < 128; kk += 32) {
    *(s8v*)&As[arow * LDT + akc] =
        *(const s8v*)&H[(size_t)(tileM + arow) * BN_DIM + kk + akc];
#pragma unroll
    for (int i = 0; i < 2; ++i) {
      int idx = t + i * 256;
      int brow = idx >> 2, bkc = (idx & 3) * 8;
      const float* wp = &W[(size_t)(tileN + brow) * BN_DIM + kk + bkc];
      float4 w0 = *(const float4*)wp;
      float4 w1 = *(const float4*)(wp + 4);
      s8v bv;
      bv[0] = (short)f2bf(w0.x); bv[1] = (short)f2bf(w0.y);
      bv[2] = (short)f2bf(w0.z); bv[3] = (short)f2bf(w0.w);
      bv[4] = (short)f2bf(w1.x); bv[5] = (short)f2bf(w1.y);
      bv[6] = (short)f2bf(w1.z); bv[7] = (short)f2bf(w1.w);
      *(s8v*)&Bs[brow * LDT + bkc] = bv;
    }
    __syncthreads();
    int kq = (lane >> 4) * 8;
    s8v a = *(const s8v*)&As[(wave * 16 + (lane & 15)) * LDT + kq];
#pragma unroll
    for (int nt = 0; nt < 8; ++nt) {
      s8v b = *(const s8v*)&Bs[(nt * 16 + (lane & 15)) * LDT + kq];
      acc[nt] = __builtin_amdgcn_mfma_f32_16x16x32_bf16(a, b, acc[nt], 0, 0, 0);
    }
    __syncthreads();
  }
#pragma unroll
  for (int nt = 0; nt < 8; ++nt) {
    int n = tileN + nt * 16 + (lane & 15);
    float bs = bias[n];
#pragma unroll
    for (int r = 0; r < 4; ++r) {
      int gm = tileM + wave * 16 + (lane >> 4) * 4 + r;
      size_t oi = (size_t)gm * D_DIM + n;
      out[oi] = acc[nt][r] + bs + out[oi];
    }
  }
}

// ---------------------------------------------------------------------------
extern "C" void kernel_launch(void* const* d_in, const int* in_sizes, int n_in,
                              void* d_out, int out_size, void* d_ws, size_t ws_size,
                              hipStream_t stream) {
  const float* x      = (const float*)d_in[0];
  const float* res    = (const float*)d_in[1];
  const float* gamma  = (const float*)d_in[2];
  const float* beta   = (const float*)d_in[3];
  const float* W_down = (const float*)d_in[4];
  const float* b_down = (const float*)d_in[5];
  const float* W_up   = (const float*)d_in[6];
  const float* b_up   = (const float*)d_in[7];
  float* out = (float*)d_out;

  // ws: norm [M,1024] bf16 (64MB) + h1 [M,128] bf16 (8MB) = 72MB
  unsigned short* ws_norm = (unsigned short*)d_ws;
  unsigned short* ws_h1   = ws_norm + (size_t)M_DIM * D_DIM;

  add_ln_kernel<<<M_DIM / 4, 256, 0, stream>>>(x, res, gamma, beta, ws_norm, out);
  gemm_down<<<M_DIM / 64, 256, 0, stream>>>(ws_norm, W_down, b_down, ws_h1);
  gemm_up<<<dim3(M_DIM / 64, D_DIM / 128), 256, 0, stream>>>(ws_h1, W_up, b_up, out);
}

// Round 3
// 415.976 us; speedup vs baseline: 1.0630x; 1.0630x over previous
//
#include <hip/hip_runtime.h>

// S=4096, B=8, D=1024, BN=128; M = S*B = 32768 rows. fp32 I/O, bf16 MFMA inside.
#define S_DIM 4096
#define B_DIM 8
#define D_DIM 1024
#define BN_DIM 128
#define M_DIM (S_DIM * B_DIM)
#define LDT 40   // LDS row stride (ushorts) for GEMM staging tiles
#define CLD 132  // LDS row stride (floats) for epilogue transpose

typedef short s8v __attribute__((ext_vector_type(8)));
typedef float f4v __attribute__((ext_vector_type(4)));

__device__ __forceinline__ unsigned short f2bf(float f) {
  union { unsigned int i; float f; } v; v.f = f;
  unsigned int r = v.i + 0x7FFFu + ((v.i >> 16) & 1u);
  return (unsigned short)(r >> 16);
}
__device__ __forceinline__ float bf2f(unsigned short u) {
  union { unsigned int i; float f; } v; v.i = ((unsigned int)u) << 16; return v.f;
}

// ---------------------------------------------------------------------------
// Prep: Wd'[n,k] = W_down[n,k]*gamma[k] (bf16); bd'[n] = b_down[n] + W_down[n,:]·beta;
//       Wu' = bf16(W_up). Blocks 0..127: row n of W_down. Blocks 128..159: W_up chunks.
// ---------------------------------------------------------------------------
__global__ __launch_bounds__(256) void prep_kernel(
    const float* __restrict__ Wd_f, const float* __restrict__ bd_f,
    const float* __restrict__ Wu_f, const float* __restrict__ gamma,
    const float* __restrict__ beta,
    unsigned short* __restrict__ Wd, float* __restrict__ bd,
    unsigned short* __restrict__ Wu) {
  __shared__ float red[4];
  int t = threadIdx.x;
  if (blockIdx.x < 128) {
    int n = blockIdx.x, k = t * 4;
    float4 w = *(const float4*)&Wd_f[n * 1024 + k];
    float4 g = *(const float4*)&gamma[k];
    float4 bt = *(const float4*)&beta[k];
    ushort4 o;
    o.x = f2bf(w.x * g.x); o.y = f2bf(w.y * g.y);
    o.z = f2bf(w.z * g.z); o.w = f2bf(w.w * g.w);
    *(ushort4*)&Wd[n * 1024 + k] = o;
    float bs = w.x * bt.x + w.y * bt.y + w.z * bt.z + w.w * bt.w;
#pragma unroll
    for (int ofs = 32; ofs >= 1; ofs >>= 1) bs += __shfl_xor(bs, ofs, 64);
    if ((t & 63) == 0) red[t >> 6] = bs;
    __syncthreads();
    if (t == 0) bd[n] = bd_f[n] + red[0] + red[1] + red[2] + red[3];
  } else {
    int j = blockIdx.x - 128;
#pragma unroll
    for (int c = 0; c < 4; ++c) {
      int idx = j * 4096 + c * 1024 + t * 4;
      float4 w = *(const float4*)&Wu_f[idx];
      ushort4 o;
      o.x = f2bf(w.x); o.y = f2bf(w.y); o.z = f2bf(w.z); o.w = f2bf(w.w);
      *(ushort4*)&Wu[idx] = o;
    }
    __syncthreads();  // keep barrier count uniform (block-uniform branch, but cheap)
  }
}

// ---------------------------------------------------------------------------
// K1: y = x + res^T -> bf16 ws; stats (mu, rstd) per row. 2 rows per wave.
// ---------------------------------------------------------------------------
__global__ __launch_bounds__(256) void add_ln_kernel(
    const float* __restrict__ x, const float* __restrict__ res,
    unsigned short* __restrict__ y, float2* __restrict__ stats) {
  int wave = threadIdx.x >> 6, lane = threadIdx.x & 63;
  int row0 = blockIdx.x * 8 + wave * 2;

  float4 xa[2][4], ra[2][4];
#pragma unroll
  for (int p = 0; p < 2; ++p) {
    int row = row0 + p;
    const float* xr = x + (size_t)row * D_DIM;
    const float* rr = res + ((size_t)(row & 7) * S_DIM + (row >> 3)) * D_DIM;
#pragma unroll
    for (int c = 0; c < 4; ++c) {
      int e = c * 256 + lane * 4;
      xa[p][c] = *(const float4*)&xr[e];
      ra[p][c] = *(const float4*)&rr[e];
    }
  }
  float sum[2] = {0.f, 0.f}, sq[2] = {0.f, 0.f};
#pragma unroll
  for (int p = 0; p < 2; ++p)
#pragma unroll
    for (int c = 0; c < 4; ++c) {
      xa[p][c].x += ra[p][c].x; xa[p][c].y += ra[p][c].y;
      xa[p][c].z += ra[p][c].z; xa[p][c].w += ra[p][c].w;
      sum[p] += xa[p][c].x + xa[p][c].y + xa[p][c].z + xa[p][c].w;
      sq[p] += xa[p][c].x * xa[p][c].x + xa[p][c].y * xa[p][c].y +
               xa[p][c].z * xa[p][c].z + xa[p][c].w * xa[p][c].w;
    }
#pragma unroll
  for (int ofs = 32; ofs >= 1; ofs >>= 1) {
    sum[0] += __shfl_xor(sum[0], ofs, 64);
    sq[0]  += __shfl_xor(sq[0], ofs, 64);
    sum[1] += __shfl_xor(sum[1], ofs, 64);
    sq[1]  += __shfl_xor(sq[1], ofs, 64);
  }
#pragma unroll
  for (int p = 0; p < 2; ++p) {
    int row = row0 + p;
    float mu = sum[p] * (1.f / D_DIM);
    float var = sq[p] * (1.f / D_DIM) - mu * mu;
    float rstd = rsqrtf(var + 1e-5f);
    if (lane == 0) stats[row] = make_float2(mu, rstd);
    unsigned short* yr = y + (size_t)row * D_DIM;
#pragma unroll
    for (int c = 0; c < 4; ++c) {
      int e = c * 256 + lane * 4;
      ushort4 o;
      o.x = f2bf(xa[p][c].x); o.y = f2bf(xa[p][c].y);
      o.z = f2bf(xa[p][c].z); o.w = f2bf(xa[p][c].w);
      *(ushort4*)&yr[e] = o;
    }
  }
}

// ---------------------------------------------------------------------------
// K2: H = relu(norm(y) @ Wd'^T + bd')  [M,128]; normalize during A staging.
// ---------------------------------------------------------------------------
__global__ __launch_bounds__(256) void gemm_down(
    const unsigned short* __restrict__ Y,    // [M,1024] bf16
    const unsigned short* __restrict__ Wd,   // [128,1024] bf16 (gamma folded)
    const float* __restrict__ bd,            // [128] fp32 (beta folded)
    const float2* __restrict__ stats,        // [M] (mu, rstd)
    unsigned short* __restrict__ H) {        // [M,128] bf16
  __shared__ unsigned short As[64 * LDT];
  __shared__ unsigned short Bs[128 * LDT];
  int t = threadIdx.x, wave = t >> 6, lane = t & 63;
  int tileM = blockIdx.x * 64;
  int arow = t >> 2, akc = (t & 3) * 8;
  float2 st = stats[tileM + arow];
  float rstd = st.y, nmu = -st.x * st.y;  // v*rstd + nmu

  f4v acc[8];
#pragma unroll
  for (int i = 0; i < 8; ++i) acc[i] = (f4v){0.f, 0.f, 0.f, 0.f};

  for (int kk = 0; kk < 1024; kk += 32) {
    s8v yv = *(const s8v*)&Y[(size_t)(tileM + arow) * 1024 + kk + akc];
    s8v av;
#pragma unroll
    for (int j = 0; j < 8; ++j)
      av[j] = (short)f2bf(bf2f((unsigned short)yv[j]) * rstd + nmu);
    *(s8v*)&As[arow * LDT + akc] = av;
#pragma unroll
    for (int i = 0; i < 2; ++i) {
      int idx = t + i * 256;
      int brow = idx >> 2, bkc = (idx & 3) * 8;
      *(s8v*)&Bs[brow * LDT + bkc] = *(const s8v*)&Wd[(size_t)brow * 1024 + kk + bkc];
    }
    __syncthreads();
    int kq = (lane >> 4) * 8;
    s8v a = *(const s8v*)&As[(wave * 16 + (lane & 15)) * LDT + kq];
#pragma unroll
    for (int nt = 0; nt < 8; ++nt) {
      s8v b = *(const s8v*)&Bs[(nt * 16 + (lane & 15)) * LDT + kq];
      acc[nt] = __builtin_amdgcn_mfma_f32_16x16x32_bf16(a, b, acc[nt], 0, 0, 0);
    }
    __syncthreads();
  }
#pragma unroll
  for (int nt = 0; nt < 8; ++nt) {
    int n = nt * 16 + (lane & 15);
    float bs = bd[n];
#pragma unroll
    for (int r = 0; r < 4; ++r) {
      int m = wave * 16 + (lane >> 4) * 4 + r;
      float val = acc[nt][r] + bs;
      val = val > 0.f ? val : 0.f;
      H[(size_t)(tileM + m) * BN_DIM + n] = f2bf(val);
    }
  }
}

// ---------------------------------------------------------------------------
// K3: out = H @ Wu'^T + b_up + y (bf16 shortcut). LDS-transpose epilogue.
// ---------------------------------------------------------------------------
__global__ __launch_bounds__(256) void gemm_up(
    const unsigned short* __restrict__ H,    // [M,128] bf16
    const unsigned short* __restrict__ Wu,   // [1024,128] bf16
    const float* __restrict__ bias,          // [1024] fp32
    const unsigned short* __restrict__ Y,    // [M,1024] bf16 shortcut
    float* __restrict__ out) {               // [M,1024] fp32
  __shared__ unsigned short As[64 * LDT];
  __shared__ unsigned short Bs[128 * LDT];
  __shared__ float Cs[64 * CLD];
  int t = threadIdx.x, wave = t >> 6, lane = t & 63;
  int tileM = blockIdx.x * 64;
  int tileN = blockIdx.y * 128;

  f4v acc[8];
#pragma unroll
  for (int i = 0; i < 8; ++i) acc[i] = (f4v){0.f, 0.f, 0.f, 0.f};

  int arow = t >> 2, akc = (t & 3) * 8;
#pragma unroll
  for (int kk = 0; kk < 128; kk += 32) {
    *(s8v*)&As[arow * LDT + akc] =
        *(const s8v*)&H[(size_t)(tileM + arow) * BN_DIM + kk + akc];
#pragma unroll
    for (int i = 0; i < 2; ++i) {
      int idx = t + i * 256;
      int brow = idx >> 2, bkc = (idx & 3) * 8;
      *(s8v*)&Bs[brow * LDT + bkc] =
          *(const s8v*)&Wu[(size_t)(tileN + brow) * BN_DIM + kk + bkc];
    }
    __syncthreads();
    int kq = (lane >> 4) * 8;
    s8v a = *(const s8v*)&As[(wave * 16 + (lane & 15)) * LDT + kq];
#pragma unroll
    for (int nt = 0; nt < 8; ++nt) {
      s8v b = *(const s8v*)&Bs[(nt * 16 + (lane & 15)) * LDT + kq];
      acc[nt] = __builtin_amdgcn_mfma_f32_16x16x32_bf16(a, b, acc[nt], 0, 0, 0);
    }
    __syncthreads();
  }
  // acc + bias -> Cs
#pragma unroll
  for (int nt = 0; nt < 8; ++nt) {
    int nl = nt * 16 + (lane & 15);
    float bs = bias[tileN + nl];
#pragma unroll
    for (int r = 0; r < 4; ++r) {
      int m = wave * 16 + (lane >> 4) * 4 + r;
      Cs[m * CLD + nl] = acc[nt][r] + bs;
    }
  }
  __syncthreads();
  // coalesced fp32 writes: 16 threads per row, 8 floats per thread
#pragma unroll
  for (int pass = 0; pass < 4; ++pass) {
    int m = pass * 16 + (t >> 4);
    int col = (t & 15) * 8;
    size_t gbase = (size_t)(tileM + m) * D_DIM + tileN + col;
    s8v yv = *(const s8v*)&Y[gbase];
    const float* cs = &Cs[m * CLD + col];
    float4 o0, o1;
    o0.x = cs[0] + bf2f((unsigned short)yv[0]);
    o0.y = cs[1] + bf2f((unsigned short)yv[1]);
    o0.z = cs[2] + bf2f((unsigned short)yv[2]);
    o0.w = cs[3] + bf2f((unsigned short)yv[3]);
    o1.x = cs[4] + bf2f((unsigned short)yv[4]);
    o1.y = cs[5] + bf2f((unsigned short)yv[5]);
    o1.z = cs[6] + bf2f((unsigned short)yv[6]);
    o1.w = cs[7] + bf2f((unsigned short)yv[7]);
    *(float4*)&out[gbase] = o0;
    *(float4*)&out[gbase + 4] = o1;
  }
}

// ---------------------------------------------------------------------------
extern "C" void kernel_launch(void* const* d_in, const int* in_sizes, int n_in,
                              void* d_out, int out_size, void* d_ws, size_t ws_size,
                              hipStream_t stream) {
  const float* x      = (const float*)d_in[0];
  const float* res    = (const float*)d_in[1];
  const float* gamma  = (const float*)d_in[2];
  const float* beta   = (const float*)d_in[3];
  const float* W_down = (const float*)d_in[4];
  const float* b_down = (const float*)d_in[5];
  const float* W_up   = (const float*)d_in[6];
  const float* b_up   = (const float*)d_in[7];
  float* out = (float*)d_out;

  // ws layout: y [M,1024] bf16 | h1 [M,128] bf16 | stats [M] float2 |
  //            Wd' [128,1024] bf16 | bd' [128] f32 | Wu' [1024,128] bf16
  unsigned short* ws_y  = (unsigned short*)d_ws;
  unsigned short* ws_h1 = ws_y + (size_t)M_DIM * D_DIM;
  float2* ws_stats      = (float2*)(ws_h1 + (size_t)M_DIM * BN_DIM);
  unsigned short* ws_wd = (unsigned short*)(ws_stats + M_DIM);
  float* ws_bd          = (float*)(ws_wd + 128 * 1024);
  unsigned short* ws_wu = (unsigned short*)(ws_bd + 128);

  prep_kernel<<<160, 256, 0, stream>>>(W_down, b_down, W_up, gamma, beta,
                                       ws_wd, ws_bd, ws_wu);
  add_ln_kernel<<<M_DIM / 8, 256, 0, stream>>>(x, res, ws_y, ws_stats);
  gemm_down<<<M_DIM / 64, 256, 0, stream>>>(ws_y, ws_wd, ws_bd, ws_stats, ws_h1);
  gemm_up<<<dim3(M_DIM / 64, D_DIM / 128), 256, 0, stream>>>(ws_h1, ws_wu, b_up,
                                                             ws_y, out);
}